// Round 8
// baseline (266.835 us; speedup 1.0000x reference)
//
#include <hip/hip_runtime.h>
#include <hip/hip_bf16.h>
#include <math.h>

typedef __hip_bfloat16 bf16;

#define NRES 256
#define LC   32
#define HCH  128
#define ECH  64
#define NH   4
#define NCA  14
#define KNNK 8
#define DH   32
#define NKE  (NRES*KNNK)      // 2048
#define NEDGE (NKE+NRES)      // 2304
#define NE1  64
#define NROWS (NRES*NCA)      // 3584

// distance tables: nearest-neighbor, h=1/256, domain [0,12]
#define NT     3073
#define TSCALE 256.0f
#define DMAXT  12.0f

// ---- fp32 converted-input region offsets (floats) ----
#define O_RESH   0
#define O_RESX   458752
#define O_LPOS   469504
#define O_LFEAT  469888
#define O_LMASK  486272
#define O_LNG    486400
#define O_LNB    486528
#define O_LN1G   486656
#define O_LN1B   486784
#define O_WQ     486912
#define O_WK     503296
#define O_WV     519680
#define O_WKL    536064
#define O_WVL    552448
#define O_WO     568832
#define O_WOL    585216
#define O_WOL1   601600
#define O_TIW1   617984
#define O_TIB1   658944
#define O_TIW2   659072
#define O_TIB2   659200
#define O_SDW1   659204
#define O_SDB1   667396
#define O_SDW2   667524
#define O_SDB2   668036
#define O_SD1W1  668040
#define O_SD1B1  676232
#define O_SD1W2  676360
#define O_SD1B2  676872
#define TOTCVT   676876
#define CVT_RSV  676880

#define OUTX_OFF 458752
#define OUTL_OFF 469504

#define CVB  ((TOTCVT+255)/256)          // 2645 convert blocks
#define NEB  ((NT*64+255)/256)           // 769 E-table blocks
#define NGEMM 291                        // 97 row-tiles x 3 matrices

__constant__ int c_counts[21] = {14,5,11,8,8,6,9,9,4,10,8,8,9,8,11,7,6,7,14,12,7};

using bfrag = __attribute__((ext_vector_type(8))) short;   // 8 bf16 (4 VGPRs)
using f32x4 = __attribute__((ext_vector_type(4))) float;   // 4 fp32

__device__ __forceinline__ float b2f(bf16 x){ return __bfloat162float(x); }
__device__ __forceinline__ float sspf(float x){
  return fmaxf(x,0.f) + log1pf(expf(-fabsf(x))) - 0.6931471805599453f;
}
__device__ __forceinline__ float bflo(unsigned u){ return __uint_as_float(u<<16); }
__device__ __forceinline__ float bfhi(unsigned u){ return __uint_as_float(u & 0xffff0000u); }
__device__ __forceinline__ unsigned short f2bs(float v){ bf16 b=__float2bfloat16(v); return *(unsigned short*)&b; }
__device__ __forceinline__ unsigned pack2(float a, float b){
  return (unsigned)f2bs(a) | ((unsigned)f2bs(b)<<16);
}
__device__ __forceinline__ int ccount(int s){ return c_counts[s<0?0:(s>20?20:s)]; }
__device__ __forceinline__ void storeOut(void* out, int isbf, int idx, float v){
  if (isbf) ((bf16*)out)[idx] = __float2bfloat16(v);
  else      ((float*)out)[idx] = v;
}

// ---------------------------------------------------------------- kcvt: inputs -> fp32 + E-table blocks
__global__ __launch_bounds__(256) void kcvt(
    const void* s0,const void* s1,const void* s2,const void* s3,const void* s4,
    const void* s5,const void* s6,const void* s7,const void* s8,const void* s9,
    const void* s10,const void* s11,const void* s12,const void* s13,const void* s14,
    const void* s15,const void* s16,const void* s17,const void* s18,const void* s19,
    const void* s20,const void* s21,const void* s22,const void* s23,const void* s24,
    const void* s25,const void* s26,const void* s27,const void* s28,
    float* __restrict__ dst, int* __restrict__ flag, float* __restrict__ etab)
{
  int bb = blockIdx.x;
  int tid = threadIdx.x;
  if (bb >= CVB){
    int idx = (bb - CVB)*256 + tid;
    if (idx < NT*64){
      int bq = idx >> 6, k = idx & 63;
      const float step = 10.0f/63.0f;
      const float coef = -0.5f/(step*step);
      float t = (float)bq*(1.0f/256.0f) - step*(float)k;
      etab[idx] = expf(coef*t*t);
    }
    return;
  }
  __shared__ int sflag;
  if (tid < 64){
    unsigned w = ((const unsigned*)s0)[tid];
    unsigned lo = w & 0xFFFFu;
    int ee = (lo >> 7) & 0xFF;
    int good = (lo == 0u) || (ee >= 121 && ee <= 133);
    unsigned long long m = __ballot(good);
    if (tid == 0){
      sflag = (__popcll(m) >= 40) ? 1 : 0;
      if (blockIdx.x == 0) flag[0] = sflag;
    }
  }
  __syncthreads();
  int isbf = sflag;
  int g = bb*256 + tid;
  if (g >= TOTCVT) return;
  const void* src; int l;
  if      (g < O_RESX ) { src=s0;  l=g; }
  else if (g < O_LPOS ) { src=s1;  l=g-O_RESX; }
  else if (g < O_LFEAT) { src=s2;  l=g-O_LPOS; }
  else if (g < O_LMASK) { src=s3;  l=g-O_LFEAT; }
  else if (g < O_LNG  ) { src=s4;  l=g-O_LMASK; }
  else if (g < O_LNB  ) { src=s5;  l=g-O_LNG; }
  else if (g < O_LN1G ) { src=s6;  l=g-O_LNB; }
  else if (g < O_LN1B ) { src=s7;  l=g-O_LN1G; }
  else if (g < O_WQ   ) { src=s8;  l=g-O_LN1B; }
  else if (g < O_WK   ) { src=s9;  l=g-O_WQ; }
  else if (g < O_WV   ) { src=s10; l=g-O_WK; }
  else if (g < O_WKL  ) { src=s11; l=g-O_WV; }
  else if (g < O_WVL  ) { src=s12; l=g-O_WKL; }
  else if (g < O_WO   ) { src=s13; l=g-O_WVL; }
  else if (g < O_WOL  ) { src=s14; l=g-O_WO; }
  else if (g < O_WOL1 ) { src=s15; l=g-O_WOL; }
  else if (g < O_TIW1 ) { src=s16; l=g-O_WOL1; }
  else if (g < O_TIB1 ) { src=s17; l=g-O_TIW1; }
  else if (g < O_TIW2 ) { src=s18; l=g-O_TIB1; }
  else if (g < O_TIB2 ) { src=s19; l=g-O_TIW2; }
  else if (g < O_SDW1 ) { src=s20; l=0; }
  else if (g < O_SDB1 ) { src=s21; l=g-O_SDW1; }
  else if (g < O_SDW2 ) { src=s22; l=g-O_SDB1; }
  else if (g < O_SDB2 ) { src=s23; l=g-O_SDW2; }
  else if (g < O_SD1W1) { src=s24; l=g-O_SDB2; }
  else if (g < O_SD1B1) { src=s25; l=g-O_SD1W1; }
  else if (g < O_SD1W2) { src=s26; l=g-O_SD1B1; }
  else if (g < O_SD1B2) { src=s27; l=g-O_SD1W2; }
  else                  { src=s28; l=g-O_SD1B2; }
  float v = isbf ? b2f(((const bf16*)src)[l]) : ((const float*)src)[l];
  dst[g] = v;
}

// ---------------------------------------------------------------- kprep: table GEMM + transpose + inv_row
// ctab row (68 u32, 272B): [0]=sig01 [1]=sig23 [2+t]=c(2t,2t+1) t=0..63, [66..67]=0
__global__ __launch_bounds__(256) void kprep(const float* __restrict__ cvt, const float* __restrict__ Etab,
    const int* __restrict__ row1,
    unsigned* __restrict__ ctab, float* __restrict__ sig1T,
    float* __restrict__ wt, int* __restrict__ inv_row)
{
  int b = blockIdx.x, tid = threadIdx.x;
  if (b >= NGEMM){
    int cb = b - NGEMM;
    if (cb < 640){
      int gid = cb*256 + tid;
      int m = gid >> 14;
      int j = gid & 16383;
      int oo = j >> 7, c = j & 127;
      float v;
      switch(m){
        case 0: v = cvt[O_WQ  + j]; break;
        case 1: v = cvt[O_WK  + j]; break;
        case 2: v = cvt[O_WV  + j]; break;
        case 3: v = cvt[O_WO  + j]; break;
        case 4: v = cvt[O_WKL + j]; break;
        case 5: v = cvt[O_WVL + j]; break;
        case 6: v = cvt[O_WOL + j]; break;
        case 7: v = cvt[O_WOL1+ j]; break;
        case 8: v = cvt[O_TIW1 + oo*320 + c]; break;
        default:v = cvt[O_TIW1 + oo*320 + 128 + c]; break;
      }
      wt[m*16384 + c*128 + oo] = v;
    } else {
      inv_row[tid] = -1;
      __syncthreads();
      if (tid < NE1) inv_row[row1[tid] & 255] = tid;
    }
    return;
  }
  // GEMM tile: 32 table rows x 128 outputs for matrix m (0=Ti_c, 1=SDW1, 2=SD1W1)
  __shared__ float Wl[128*68];
  __shared__ float Et[32*68];
  __shared__ float H[32*132];
  __shared__ float W2[4*132];
  __shared__ float W2b[4];
  int mt = b % 97, m = b / 97;
  int r0 = mt*32;
  int nr = (NT - r0 < 32) ? (NT - r0) : 32;

  for (int idx=tid; idx<8192; idx+=256){
    int o=idx>>6, k=idx&63;
    float v = (m==0) ? cvt[O_TIW1 + o*320 + 256 + k]
            : (m==1) ? cvt[O_SDW1 + idx]
                     : cvt[O_SD1W1 + idx];
    Wl[o*68+k] = v;
  }
  for (int idx=tid; idx<nr*64; idx+=256){
    int r=idx>>6, k=idx&63;
    Et[r*68+k] = Etab[(size_t)(r0+r)*64 + k];
  }
  if (m >= 1){
    int wbase = (m==1)? O_SDW2 : O_SD1W2;
    int bbase = (m==1)? O_SDB2 : O_SD1B2;
    for (int idx=tid; idx<512; idx+=256)
      W2[(idx>>7)*132 + (idx&127)] = cvt[wbase + idx];
    if (tid < 4) W2b[tid] = cvt[bbase + tid];
  }
  __syncthreads();

  int o = tid & 127, g = tid >> 7;
  int boff = (m==0)? O_TIB1 : (m==1)? O_SDB1 : O_SD1B1;
  float bias = cvt[boff + o];
  float acc[16];
  #pragma unroll
  for (int i=0;i<16;i++) acc[i] = bias;
  const float* wrow = Wl + o*68;
  const float* ebase = Et + g*16*68;
  for (int kc=0; kc<16; kc++){
    float4 w4 = *(const float4*)(wrow + kc*4);
    #pragma unroll
    for (int i=0;i<16;i++){
      float4 e4 = *(const float4*)(ebase + i*68 + kc*4);
      acc[i] += e4.x*w4.x;
      acc[i] += e4.y*w4.y;
      acc[i] += e4.z*w4.z;
      acc[i] += e4.w*w4.w;
    }
  }

  if (m == 0){
    #pragma unroll
    for (int i=0;i<16;i++){
      int row = r0 + g*16 + i;
      float c = acc[i];
      float cn = __shfl_xor(c, 1);
      if (row < NT && !(o&1))
        ctab[(size_t)row*68 + 2 + (o>>1)] = pack2(c, cn);
    }
    if (o < 2 && g == 0){
      for (int i=0;i<32;i++){
        int row = r0 + i;
        if (row < NT) ctab[(size_t)row*68 + 66 + o] = 0u;
      }
    }
    return;
  }
  // m>=1: relu -> H, then 128->4 tail dots
  #pragma unroll
  for (int i=0;i<16;i++)
    H[(g*16+i)*132 + o] = fmaxf(acc[i], 0.f);
  __syncthreads();
  if (tid < 128){
    int r = tid >> 2, hh = tid & 3;
    int row = r0 + r;
    if (r < nr){
      float s = W2b[hh];
      const float* hr = H + r*132;
      const float* w2r = W2 + hh*132;
      for (int o2=0;o2<128;o2++) s += hr[o2]*w2r[o2];
      if (m == 1){
        float s1 = __shfl_down(s,1);
        float s2 = __shfl_down(s,2);
        float s3 = __shfl_down(s,3);
        if (hh == 0){
          ctab[(size_t)row*68 + 0] = pack2(s, s1);
          ctab[(size_t)row*68 + 1] = pack2(s2, s3);
        }
      } else {
        sig1T[row*4 + hh] = s;
      }
    }
  }
}

// ------------------------------------------------- kProjAll: b<672 LN+proj tiles; 672..735 KNN; 736..799 ligand
__global__ __launch_bounds__(256) void kProjAll(
    const float* __restrict__ cvt, const float* __restrict__ wt, const int* __restrict__ batch,
    float* __restrict__ resHn, bf16* __restrict__ Qw16, bf16* __restrict__ Kw16,
    bf16* __restrict__ Vw16, bf16* __restrict__ TQw16, bf16* __restrict__ TKw16,
    int* __restrict__ nbr, float* __restrict__ lf, bf16* __restrict__ Klw16, bf16* __restrict__ Vlw16)
{
  __shared__ float Xs[16*129];
  __shared__ float x2[2][HCH];
  __shared__ float sred2[2][2];
  int bb = blockIdx.x, tid = threadIdx.x;

  if (bb < 672){
    int m = bb / 224;
    int rt = (bb % 224) * 16;
    for (int i=tid; i<16*128; i+=256){
      int r=i>>7, c=i&127;
      Xs[r*129+c] = cvt[O_RESH + (rt+r)*HCH + c];
    }
    __syncthreads();
    {
      int wave = tid>>6, lane = tid&63;
      int r = wave*4 + (lane>>4);
      int cb = lane & 15;
      float s=0;
      #pragma unroll
      for (int j=0;j<8;j++) s += Xs[r*129 + cb + 16*j];
      #pragma unroll
      for (int off=1; off<16; off<<=1) s += __shfl_xor(s, off);
      float mu = s*(1.f/HCH);
      float q=0;
      #pragma unroll
      for (int j=0;j<8;j++){ float dv = Xs[r*129+cb+16*j]-mu; q += dv*dv; }
      #pragma unroll
      for (int off=1; off<16; off<<=1) q += __shfl_xor(q, off);
      float inv = rsqrtf(q*(1.f/HCH) + 1e-5f);
      #pragma unroll
      for (int j=0;j<8;j++){
        int c = cb + 16*j;
        float xh = (Xs[r*129+c]-mu)*inv*cvt[O_LNG+c] + cvt[O_LNB+c];
        Xs[r*129+c] = xh;
        if (m==0) resHn[(rt+r)*HCH+c] = xh;
      }
    }
    __syncthreads();
    int tc = (tid & 31) * 4;
    int tr = (tid >> 5) * 2;
    const float* W = wt + m*16384;
    float a00=0,a01=0,a02=0,a03=0, a10=0,a11=0,a12=0,a13=0;
    for (int c=0;c<HCH;c++){
      float4 w4 = *(const float4*)(W + c*128 + tc);
      float x0 = Xs[tr*129 + c];
      float x1 = Xs[(tr+1)*129 + c];
      a00 += x0*w4.x; a01 += x0*w4.y; a02 += x0*w4.z; a03 += x0*w4.w;
      a10 += x1*w4.x; a11 += x1*w4.y; a12 += x1*w4.z; a13 += x1*w4.w;
    }
    bf16* out = (m==0)? Qw16 : (m==1)? Kw16 : Vw16;
    {
      unsigned* o0 = (unsigned*)(out + (rt+tr  )*HCH + tc);
      unsigned* o1 = (unsigned*)(out + (rt+tr+1)*HCH + tc);
      o0[0]=pack2(a00,a01); o0[1]=pack2(a02,a03);
      o1[0]=pack2(a10,a11); o1[1]=pack2(a12,a13);
    }
    if (m == 2) return;
    __syncthreads();
    Xs[tr*129+tc]=a00; Xs[tr*129+tc+1]=a01; Xs[tr*129+tc+2]=a02; Xs[tr*129+tc+3]=a03;
    Xs[(tr+1)*129+tc]=a10; Xs[(tr+1)*129+tc+1]=a11; Xs[(tr+1)*129+tc+2]=a12; Xs[(tr+1)*129+tc+3]=a13;
    __syncthreads();
    const float* W2 = wt + (8+m)*16384;
    a00=0;a01=0;a02=0;a03=0; a10=0;a11=0;a12=0;a13=0;
    for (int c=0;c<HCH;c++){
      float4 w4 = *(const float4*)(W2 + c*128 + tc);
      float x0 = Xs[tr*129 + c];
      float x1 = Xs[(tr+1)*129 + c];
      a00 += x0*w4.x; a01 += x0*w4.y; a02 += x0*w4.z; a03 += x0*w4.w;
      a10 += x1*w4.x; a11 += x1*w4.y; a12 += x1*w4.z; a13 += x1*w4.w;
    }
    bf16* out2 = m ? TKw16 : TQw16;
    {
      unsigned* o0 = (unsigned*)(out2 + (rt+tr  )*HCH + tc);
      unsigned* o1 = (unsigned*)(out2 + (rt+tr+1)*HCH + tc);
      o0[0]=pack2(a00,a01); o0[1]=pack2(a02,a03);
      o1[0]=pack2(a10,a11); o1[1]=pack2(a12,a13);
    }
    return;
  }

  if (bb < 736){
    // KNN: one wave per residue
    int wave = tid>>6, lane = tid&63;
    int n = (bb-672)*4 + wave;
    float cx = cvt[O_RESX+(n*NCA+1)*3+0];
    float cy = cvt[O_RESX+(n*NCA+1)*3+1];
    float cz = cvt[O_RESX+(n*NCA+1)*3+2];
    int bn = batch[n];
    float d2v[4]; int idv[4];
    #pragma unroll
    for (int t=0;t<4;t++){
      int j = lane + 64*t;
      float jx = cvt[O_RESX+(j*NCA+1)*3+0];
      float jy = cvt[O_RESX+(j*NCA+1)*3+1];
      float jz = cvt[O_RESX+(j*NCA+1)*3+2];
      float dx=cx-jx, dy=cy-jy, dz=cz-jz;
      float d2 = dx*dx+dy*dy+dz*dz;
      bool bad = (batch[j]!=bn) || (j==n);
      d2v[t] = bad ? INFINITY : d2;
      idv[t] = j;
    }
    for (int k=0;k<KNNK;k++){
      float dm = d2v[0]; int im = idv[0];
      #pragma unroll
      for (int t=1;t<4;t++)
        if (d2v[t]<dm || (d2v[t]==dm && idv[t]<im)){ dm=d2v[t]; im=idv[t]; }
      #pragma unroll
      for (int off=1; off<64; off<<=1){
        float dn = __shfl_xor(dm, off);
        int   in = __shfl_xor(im, off);
        if (dn<dm || (dn==dm && in<im)){ dm=dn; im=in; }
      }
      if (lane==0) nbr[n*KNNK+k] = im;
      #pragma unroll
      for (int t=0;t<4;t++) if (idv[t]==im) d2v[t] = INFINITY;
    }
    return;
  }

  // ligand LN + Kl/Vl: 2 rows per block
  int row = tid>>7, t = tid&127;
  int rb = (bb-736)*2 + row;
  float v = cvt[O_LFEAT + rb*HCH + t];
  float s=v;
  for (int off=1; off<64; off<<=1) s += __shfl_xor(s, off);
  if ((t&63)==0) sred2[row][t>>6]=s;
  __syncthreads();
  float mu=(sred2[row][0]+sred2[row][1])*(1.f/HCH);
  __syncthreads();
  float d=v-mu; s=d*d;
  for (int off=1; off<64; off<<=1) s += __shfl_xor(s, off);
  if ((t&63)==0) sred2[row][t>>6]=s;
  __syncthreads();
  float var=(sred2[row][0]+sred2[row][1])*(1.f/HCH);
  float xh = d*rsqrtf(var+1e-5f)*cvt[O_LN1G+t] + cvt[O_LN1B+t];
  x2[row][t]=xh; lf[rb*HCH+t]=xh;
  __syncthreads();
  const float* WKlt = wt + 4*16384;
  const float* WVlt = wt + 5*16384;
  float aK=0.f, aV=0.f;
  for (int c=0;c<HCH;c++){
    float xc=x2[row][c];
    aK += xc*WKlt[c*128+t];
    aV += xc*WVlt[c*128+t];
  }
  Klw16[rb*HCH+t]=__float2bfloat16(aK);
  Vlw16[rb*HCH+t]=__float2bfloat16(aV);
}

// ------------------------------------------------- k3: fused residue-edge; MFMA qk/aV, bf16 ctab, LDS overlay
#define PR1(cbu, tau, kau, wl, wh) \
  fa += fmaxf(bflo(tau)+bflo(kau)+bflo(cbu),0.f)*(wl) + fmaxf(bfhi(tau)+bfhi(kau)+bfhi(cbu),0.f)*(wh);

__global__ __launch_bounds__(256) void k3_edge(
    const float* __restrict__ cvt, const int* __restrict__ res_S, const int* __restrict__ nbr,
    const bf16* __restrict__ Qw16, const bf16* __restrict__ Kw16,
    const bf16* __restrict__ TQw16, const bf16* __restrict__ TKw16,
    const bf16* __restrict__ Vw16, const unsigned* __restrict__ ctab,
    float* __restrict__ r_ws, bf16* __restrict__ aVe16, float* __restrict__ dXe)
{
  __shared__ __align__(16) unsigned char UB[8192];
  __shared__ unsigned Tqp[14*66], Tkp[14*66];
  __shared__ float LG[4*16*17];
  __shared__ float FR[196];
  __shared__ __align__(16) float tw2s[132];
  __shared__ float tb2s[1], Xr[42], Xc[42], amr[14], amc[14], rpart[56], cnts[2];
  unsigned char* QbB = UB;
  unsigned char* KbB = UB + 4096;
  unsigned char* VtB = UB;

  int b = blockIdx.x, tid = threadIdx.x;
  int rr = b & 255, slot = b >> 8;
  int e  = (slot < 8) ? (rr*8 + slot) : (2048 + rr);
  int cc = (slot < 8) ? (nbr[rr*8 + slot] & 255) : rr;

  const unsigned* TQ32 = (const unsigned*)TQw16;
  const unsigned* TK32 = (const unsigned*)TKw16;

  {
    int row = tid >> 4, s16 = tid & 15;
    uint4 qv = {0u,0u,0u,0u}, kv = {0u,0u,0u,0u};
    if (row < 14){
      qv = ((const uint4*)(Qw16 + (size_t)rr*1792))[tid];
      kv = ((const uint4*)(Kw16 + (size_t)cc*1792))[tid];
    }
    int off = row*256 + ((s16 ^ (row & 7)) << 4);
    *(uint4*)(QbB + off) = qv;
    *(uint4*)(KbB + off) = kv;
  }
  for (int i = tid; i < 14*66; i += 256){
    int p = i/66, t = i - p*66;
    Tqp[i] = (t<64) ? TQ32[rr*896 + p*64 + t] : 0u;
    Tkp[i] = (t<64) ? TK32[cc*896 + p*64 + t] : 0u;
  }
  if (tid < 132) tw2s[tid] = (tid<128) ? cvt[O_TIW2+tid] : 0.f;
  if (tid == 132) tb2s[0] = cvt[O_TIB2];
  if (tid >= 136 && tid < 178){
    int i=tid-136; int p=i/3, jx=i%3;
    Xr[i] = cvt[O_RESX+(rr*NCA+p)*3+jx];
    Xc[i] = cvt[O_RESX+(cc*NCA+p)*3+jx];
  }
  if (tid >= 242 && tid < 242+NCA){
    int p=tid-242;
    amr[p] = (p < ccount(res_S[rr])) ? 1.f : 0.f;
    amc[p] = (p < ccount(res_S[cc])) ? 1.f : 0.f;
  }
  __syncthreads();

  {
    int w = tid >> 6, l = tid & 63;
    int mrow = l & 15, s = l >> 4;
    int aoff = mrow*256 + (((w*4 + s) ^ (mrow & 7)) << 4);
    bfrag a = *(const bfrag*)(QbB + aoff);
    bfrag bkf = *(const bfrag*)(KbB + aoff);
    f32x4 dacc = {0.f,0.f,0.f,0.f};
    dacc = __builtin_amdgcn_mfma_f32_16x16x32_bf16(a, bkf, dacc, 0, 0, 0);
    const float isq = 0.17677669529663687f;
    #pragma unroll
    for (int r=0;r<4;r++){
      int p = s*4 + r;
      LG[w*272 + p*17 + mrow] = dacc[r]*isq;
    }
  }

  float sgx=0.f, sgy=0.f, sgz=0.f, sgw=0.f, invd_r=0.f;
  int havePair = (tid < 196);
  if (havePair){
    int p = tid/14, q = tid%14;
    float dx=Xr[p*3]-Xc[q*3], dy=Xr[p*3+1]-Xc[q*3+1], dz=Xr[p*3+2]-Xc[q*3+2];
    float d = sqrtf(fmaxf(dx*dx+dy*dy+dz*dz, 1e-12f));
    invd_r = 1.f/(d + 1e-5f);
    int i0 = (int)(fminf(d, DMAXT)*TSCALE + 0.5f);
    const uint4* crow = (const uint4*)ctab + (size_t)i0*17;
    const unsigned* TqpRow = Tqp + p*66;
    const unsigned* TkpRow = Tkp + q*66;
    uint4 h0 = crow[0];
    sgx = bflo(h0.x); sgy = bfhi(h0.x); sgz = bflo(h0.y); sgw = bfhi(h0.y);
    float fa = tb2s[0];
    {
      uint2 ta = *(const uint2*)(TqpRow);
      uint2 ka = *(const uint2*)(TkpRow);
      float4 w0 = *(const float4*)(tw2s);
      PR1(h0.z, ta.x, ka.x, w0.x, w0.y);
      PR1(h0.w, ta.y, ka.y, w0.z, w0.w);
    }
    #pragma unroll 4
    for (int j=1;j<17;j++){
      uint4 ch = crow[j];
      int t = 4*j - 2;
      uint2 ta0 = *(const uint2*)(TqpRow + t);
      uint2 ta1 = *(const uint2*)(TqpRow + t + 2);
      uint2 ka0 = *(const uint2*)(TkpRow + t);
      uint2 ka1 = *(const uint2*)(TkpRow + t + 2);
      float4 w0 = *(const float4*)(tw2s + 2*t);
      float4 w1 = *(const float4*)(tw2s + 2*t + 4);
      PR1(ch.x, ta0.x, ka0.x, w0.x, w0.y);
      PR1(ch.y, ta0.y, ka0.y, w0.z, w0.w);
      PR1(ch.z, ta1.x, ka1.x, w1.x, w1.y);
      PR1(ch.w, ta1.y, ka1.y, w1.z, w1.w);
    }
    FR[tid] = fa;
  }
  __syncthreads();

  if (havePair){
    int p = tid/14, q = tid%14;
    LG[      p*17+q] += sgx;
    LG[272 + p*17+q] += sgy;
    LG[544 + p*17+q] += sgz;
    LG[816 + p*17+q] += sgw;
  }
  for (int i = tid; i < 128*16; i += 256){
    int qp = i >> 7, d = i & 127;
    int qq = qp*2;
    unsigned pv = 0u;
    if (qq < 14){
      const unsigned short* vs = (const unsigned short*)(Vw16 + (size_t)cc*1792);
      unsigned short v0 = vs[qq*128 + d];
      unsigned short v1 = vs[(qq+1)*128 + d];
      pv = (unsigned)v0 | ((unsigned)v1 << 16);
    }
    int slotq = qq >> 3;
    int off = d*64 + ((slotq ^ (d & 3)) << 4) + (qq & 7)*2;
    *(unsigned*)(VtB + off) = pv;
  }
  __syncthreads();

  if (tid < 56){
    int h=tid/14, pp=tid%14;
    float ap = amr[pp];
    float* rowp = LG + h*272 + pp*17;
    float row[NCA];
    float s=0;
    #pragma unroll
    for (int qq=0;qq<NCA;qq++){ row[qq]=rowp[qq]; s += row[qq]*amc[qq]; }
    rpart[h*14+pp] = s*ap;
    float m=-INFINITY;
    #pragma unroll
    for (int qq=0;qq<NCA;qq++) m=fmaxf(m,row[qq]);
    float sum=0;
    #pragma unroll
    for (int qq=0;qq<NCA;qq++){ row[qq]=expf(row[qq]-m); sum+=row[qq]; }
    float inv=1.f/sum, s2=0;
    #pragma unroll
    for (int qq=0;qq<NCA;qq++){ row[qq]=row[qq]*inv*ap*amc[qq]; s2+=row[qq]; }
    float inv2=1.f/(s2+1e-7f);
    #pragma unroll
    for (int qq=0;qq<NCA;qq++) rowp[qq]=row[qq]*inv2;
  }
  if (tid == 56){
    float sr=0, sc=0;
    for (int i=0;i<NCA;i++){ sr+=amr[i]; sc+=amc[i]; }
    cnts[0]=sr; cnts[1]=sc;
  }
  __syncthreads();
  if (tid < NH){
    float s=0;
    for (int pp=0;pp<NCA;pp++) s += rpart[tid*14+pp];
    r_ws[e*NH+tid] = s/(cnts[0]*cnts[1]);
  }
  if (tid < 196){
    int p=tid/14, q=tid%14;
    float ma = 0.25f*(LG[p*17+q] + LG[272+p*17+q] + LG[544+p*17+q] + LG[816+p*17+q]);
    FR[tid] *= ma * invd_r;
  }

  {
    int w = tid >> 6, l = tid & 63;
    int mrow = l & 15, s = l >> 4;
    bfrag pa;
    if (s < 2){
      const float* ar = LG + w*272 + mrow*17 + s*8;
      #pragma unroll
      for (int j=0;j<8;j++) pa[j] = (short)f2bs(ar[j]);
    } else {
      #pragma unroll
      for (int j=0;j<8;j++) pa[j] = (short)0;
    }
    #pragma unroll
    for (int half=0; half<2; half++){
      int dg = w*32 + half*16 + mrow;
      int boff = dg*64 + ((s ^ (dg & 3)) << 4);
      bfrag pb = *(const bfrag*)(VtB + boff);
      f32x4 dd = {0.f,0.f,0.f,0.f};
      dd = __builtin_amdgcn_mfma_f32_16x16x32_bf16(pa, pb, dd, 0, 0, 0);
      #pragma unroll
      for (int r=0;r<4;r++){
        int p = s*4 + r;
        if (p < NCA)
          aVe16[(size_t)e*1792 + w*448 + p*32 + half*16 + mrow] = __float2bfloat16(dd[r]);
      }
    }
  }
  __syncthreads();

  if (tid < NCA*3){
    int pp = tid/3, jx = tid%3;
    float a=0;
    #pragma unroll
    for (int qq=0;qq<NCA;qq++){
      float diff = Xr[pp*3+jx]-Xc[qq*3+jx];
      a += FR[pp*14+qq]*diff;
    }
    dXe[(e*NCA+pp)*3+jx] = a;
  }
}

// ------------------------------------------------- k4: per-residue; LDS-staged aVe16, 512 threads
__global__ __launch_bounds__(512) void k4_agg(
    const float* __restrict__ cvt, const int* __restrict__ res_S, const int* __restrict__ inv_row,
    const float* __restrict__ r_ws, const bf16* __restrict__ aVe16, const float* __restrict__ dXe,
    const float* __restrict__ resHn, const float* __restrict__ wt, const int* __restrict__ flag,
    float* __restrict__ resH2, float* __restrict__ resX2, void* __restrict__ d_out)
{
  int n = blockIdx.x, tid = threadIdx.x;
  __shared__ float beta[9][NH];
  __shared__ float betam[9];
  __shared__ __align__(16) unsigned short UL[9*1792];   // 32256 B staged aV rows
  __shared__ float Xs[NCA][HCH];                        // 7168 B
  // ---- phase A: coalesced stage of 9 edge rows + beta
  {
    const uint4* av4 = (const uint4*)aVe16;
    uint4* ul4 = (uint4*)UL;
    for (int i = tid; i < 9*224; i += 512){
      int k = i / 224, off = i - k*224;
      int ek = (k<KNNK)? n*KNNK+k : NKE+n;
      ul4[k*224 + off] = av4[(size_t)ek*224 + off];
    }
  }
  if (tid < NH){
    int h = tid;
    float rv[9], m=-INFINITY;
    #pragma unroll
    for (int k=0;k<9;k++){
      int ek = (k<KNNK)? n*KNNK+k : NKE+n;
      rv[k] = r_ws[ek*NH+h];
      m = fmaxf(m, rv[k]);
    }
    float s=0;
    #pragma unroll
    for (int k=0;k<9;k++){ rv[k]=expf(rv[k]-m); s+=rv[k]; }
    #pragma unroll
    for (int k=0;k<9;k++) beta[k][h]=rv[k]/s;
  }
  __syncthreads();
  // ---- phase B: betam + u-combine from LDS
  if (tid < 9) betam[tid] = 0.25f*(beta[tid][0]+beta[tid][1]+beta[tid][2]+beta[tid][3]);
  int col = tid & 127, pg = tid >> 7;      // pg in 0..3
  int h = col>>5, dd = col&31;
  float bh[9];
  #pragma unroll
  for (int k=0;k<9;k++) bh[k]=beta[k][h];
  #pragma unroll
  for (int j=0;j<4;j++){
    int p = pg + 4*j;
    if (p < NCA){
      float u=0;
      #pragma unroll
      for (int k=0;k<9;k++)
        u += bh[k]*__uint_as_float((unsigned)UL[k*1792 + h*448 + p*32 + dd] << 16);
      Xs[p][col] = sspf(u);
    }
  }
  __syncthreads();
  // ---- phase C: WO GEMM + residual + dX
  const float* WOt = wt + 3*16384;
  float acc[4] = {0.f,0.f,0.f,0.f};
  for (int c=0;c<HCH;c++){
    float w = WOt[c*128+col];
    #pragma unroll
    for (int j=0;j<4;j++){
      int p = pg + 4*j;
      if (p < NCA) acc[j] += Xs[p][c]*w;
    }
  }
  int cnt = ccount(res_S[n]);
  #pragma unroll
  for (int j=0;j<4;j++){
    int p = pg + 4*j;
    if (p < NCA){
      float am = (p<cnt)?1.f:0.f;
      float outv = (resHn[(n*NCA+p)*HCH+col] + acc[j])*am;
      resH2[(n*NCA+p)*HCH+col] = outv;
    }
  }
  if (tid < NCA*3){
    int isbf = *flag;
    int p=tid/3, jx=tid%3;
    float s=0;
    #pragma unroll
    for (int k=0;k<9;k++){
      int ek=(k<KNNK)? n*KNNK+k : NKE+n;
      s += betam[k]*dXe[(ek*NCA+p)*3+jx];
    }
    float base = cvt[O_RESX+(n*NCA+p)*3+jx];
    float v = (inv_row[n]>=0) ? base + fminf(fmaxf(s,-3.f),3.f) : base;
    resX2[(n*NCA+p)*3+jx] = v;
    storeOut(d_out, isbf, OUTX_OFF + (n*NCA+p)*3+jx, v);
  }
}

// ------------------------------------------------- k6: ligand-edge, one block per (edge, head) — 256 blocks
__global__ __launch_bounds__(256) void k6_lig(
    const float* __restrict__ cvt, const int* __restrict__ res_S,
    const int* __restrict__ row1, const int* __restrict__ col1,
    const float* __restrict__ resX2, const bf16* __restrict__ Qw16, const bf16* __restrict__ Klw16,
    const bf16* __restrict__ Vw16, const bf16* __restrict__ Vlw16, const float* __restrict__ sig1T,
    float* __restrict__ r1_ws, float* __restrict__ aVr, float* __restrict__ aVlg)
{
  __shared__ float Bq[14*33], Vrs[14*33], Bk[32*33], Vls[32*33];
  __shared__ float LG[14*33], ALs[14*33];
  __shared__ float Xr[42], Lp[96], amr[14], lm[32], s2r[14], rpart[14], cnts[2];
  int bb = blockIdx.x, tid = threadIdx.x;
  int e = bb >> 2, h = bb & 3;
  int rr = row1[e] & 255, cb = col1[e] & 3;
  const unsigned* Q32  = (const unsigned*)Qw16;
  const unsigned* V32  = (const unsigned*)Vw16;
  const unsigned* Kl32 = (const unsigned*)Klw16;
  const unsigned* Vl32 = (const unsigned*)Vlw16;

  for (int i=tid; i<224; i+=256){
    int p=i>>4, dp=i&15;
    unsigned q2 = Q32[rr*896 + p*64 + h*16 + dp];
    unsigned v2 = V32[rr*896 + p*64 + h*16 + dp];
    Bq[p*33+2*dp]  = bflo(q2); Bq[p*33+2*dp+1]  = bfhi(q2);
    Vrs[p*33+2*dp] = bflo(v2); Vrs[p*33+2*dp+1] = bfhi(v2);
  }
  for (int i=tid; i<512; i+=256){
    int q=i>>4, dp=i&15;
    unsigned k2 = Kl32[cb*2048 + q*64 + h*16 + dp];
    unsigned w2 = Vl32[cb*2048 + q*64 + h*16 + dp];
    Bk[q*33+2*dp]  = bflo(k2); Bk[q*33+2*dp+1]  = bfhi(k2);
    Vls[q*33+2*dp] = bflo(w2); Vls[q*33+2*dp+1] = bfhi(w2);
  }
  if (tid >= 8 && tid < 50){ int i=tid-8; int p=i/3,jx=i%3; Xr[i]=resX2[(rr*NCA+p)*3+jx]; }
  if (tid >= 64 && tid < 160){ int i=tid-64; Lp[i]=cvt[O_LPOS + cb*96 + i]; }
  if (tid >= 160 && tid < 174) amr[tid-160]=((tid-160) < ccount(res_S[rr]))?1.f:0.f;
  if (tid >= 192 && tid < 224) lm[tid-192]=cvt[O_LMASK + cb*LC + tid-192];
  __syncthreads();

  const float isq=0.17677669529663687f;
  for (int pair=tid; pair<448; pair+=256){
    int p=pair>>5, q=pair&31;
    float dx=Xr[p*3]-Lp[q*3], dy=Xr[p*3+1]-Lp[q*3+1], dz=Xr[p*3+2]-Lp[q*3+2];
    float d=sqrtf(fmaxf(dx*dx+dy*dy+dz*dz,1e-12f));
    int i0=(int)(fminf(d,DMAXT)*TSCALE+0.5f);
    float sg = sig1T[i0*4+h];
    float qk=0;
    #pragma unroll
    for (int dd=0;dd<DH;dd++) qk += Bq[p*33+dd]*Bk[q*33+dd];
    LG[p*33+q] = qk*isq + sg;
  }
  __syncthreads();

  if (tid < 14){
    int pp=tid; float ap=amr[pp];
    float s=0, m=-INFINITY;
    for (int qq=0;qq<LC;qq++){ float v=LG[pp*33+qq]; s+=v*lm[qq]; m=fmaxf(m,v); }
    rpart[pp]=s*ap;
    float sum=0;
    for (int qq=0;qq<LC;qq++) sum+=expf(LG[pp*33+qq]-m);
    float inv=1.f/sum, s2=0;
    for (int qq=0;qq<LC;qq++) s2+=expf(LG[pp*33+qq]-m)*inv*ap*lm[qq];
    s2r[pp]=s2/(s2+1e-7f);
  }
  if (tid==14){ float sr=0; for(int i=0;i<14;i++) sr+=amr[i]; cnts[0]=sr; }
  if (tid==15){ float sl=0; for(int i=0;i<32;i++) sl+=lm[i]; cnts[1]=sl; }
  __syncthreads();

  if (tid==0){ float s=0; for (int pp=0;pp<14;pp++) s+=rpart[pp]; r1_ws[e*NH+h]=s/(cnts[0]*cnts[1]); }
  if (tid < 32){
    int qq=tid;
    float m=-INFINITY;
    for (int pp=0;pp<14;pp++) m=fmaxf(m,LG[pp*33+qq]);
    float sum=0;
    for (int pp=0;pp<14;pp++) sum+=expf(LG[pp*33+qq]-m);
    float inv=1.f/sum, lq=lm[qq];
    for (int pp=0;pp<14;pp++){
      float a=expf(LG[pp*33+qq]-m)*inv*amr[pp]*lq;
      ALs[pp*33+qq]=a/(s2r[pp]+1e-7f);
    }
  }
  __syncthreads();

  if (tid < 14){
    int pp=tid; float ap=amr[pp];
    float m=-INFINITY;
    for (int qq=0;qq<LC;qq++) m=fmaxf(m,LG[pp*33+qq]);
    float row[LC]; float sum=0;
    for (int qq=0;qq<LC;qq++){ row[qq]=expf(LG[pp*33+qq]-m); sum+=row[qq]; }
    float inv=1.f/sum, s2=0;
    for (int qq=0;qq<LC;qq++){ row[qq]=row[qq]*inv*ap*lm[qq]; s2+=row[qq]; }
    float inv2=1.f/(s2+1e-7f);
    for (int qq=0;qq<LC;qq++) LG[pp*33+qq]=row[qq]*inv2;
  }
  __syncthreads();

  for (int j=tid;j<448;j+=256){
    int pp=j>>5, dd=j&31;
    float acc=0;
    #pragma unroll
    for (int qq=0;qq<LC;qq++) acc += LG[pp*33+qq]*Vls[qq*33+dd];
    aVr[e*1792 + h*448 + j]=acc;
  }
  for (int j=tid;j<1024;j+=256){
    int qq=j>>5, dd=j&31;
    float acc=0;
    #pragma unroll
    for (int pp=0;pp<14;pp++) acc += ALs[pp*33+qq]*Vrs[pp*33+dd];
    aVlg[e*4096 + h*1024 + j]=acc;
  }
}

// ------------------------------------------------- k78: finalize res_H3 (0..255, 256 thr) + lf2 (256..383)
__global__ __launch_bounds__(256) void k78_final(
    const int* __restrict__ inv_row, const int* __restrict__ res_S, const int* __restrict__ col1,
    const float* __restrict__ resH2, const float* __restrict__ aVr,
    const float* __restrict__ r1_ws, const float* __restrict__ aVlg, const float* __restrict__ lf,
    const float* __restrict__ wt, const int* __restrict__ flag, void* __restrict__ d_out)
{
  int bb = blockIdx.x, tid = threadIdx.x;
  if (bb < 256){
    int n = bb;
    int e = inv_row[n];
    __shared__ float G[NCA][HCH];
    if (e>=0){
      for (int j=tid;j<NCA*HCH;j+=256){
        int h=j/448, rem=j%448, pp=rem>>5, dd=rem&31;
        G[pp][h*DH+dd] = sspf(aVr[e*1792+j]);
      }
    }
    __syncthreads();
    int col = tid & 127, ph = tid >> 7;
    float acc[7];
    #pragma unroll
    for (int i=0;i<7;i++) acc[i]=0.f;
    if (e>=0){
      const float* WOlt = wt + 6*16384;
      for (int c=0;c<HCH;c++){
        float w=WOlt[c*128+col];
        #pragma unroll
        for (int i=0;i<7;i++) acc[i]+=G[ph+2*i][c]*w;
      }
    }
    int cnt=ccount(res_S[n]);
    int isbf = *flag;
    #pragma unroll
    for (int i=0;i<7;i++){
      int p = ph + 2*i;
      float am=(p<cnt)?1.f:0.f;
      float v=(resH2[(n*NCA+p)*HCH+col]+acc[i])*am;
      storeOut(d_out, isbf, (n*NCA+p)*HCH+col, v);
    }
    return;
  }
  // lf2 path (use 128 threads; rest idle)
  int rb = bb - 256;
  int b = rb>>5, q = rb&31;
  __shared__ float bw[NE1][NH];
  __shared__ float xs[HCH];
  if (tid<NH){
    int h=tid;
    float m=-INFINITY;
    for (int e=0;e<NE1;e++) if ((col1[e]&3)==b) m=fmaxf(m, r1_ws[e*NH+h]);
    float s=0;
    for (int e=0;e<NE1;e++) if ((col1[e]&3)==b) s+=expf(r1_ws[e*NH+h]-m);
    for (int e=0;e<NE1;e++) bw[e][h] = ((col1[e]&3)==b)? expf(r1_ws[e*NH+h]-m)/s : 0.f;
  }
  __syncthreads();
  if (tid < 128){
    int h=tid>>5, dd=tid&31;
    float u=0;
    for (int e=0;e<NE1;e++) u += bw[e][h]*aVlg[e*4096 + h*1024 + q*32 + dd];
    xs[tid]=sspf(u);
  }
  __syncthreads();
  if (tid < 128){
    const float* WOl1t = wt + 7*16384;
    float acc=0;
    for (int c=0;c<HCH;c++) acc += xs[c]*WOl1t[c*128+tid];
    float v = lf[rb*HCH+tid] + acc;
    storeOut(d_out, *flag, OUTL_OFF + rb*HCH+tid, v);
  }
}

// ================================================================ launch
extern "C" void kernel_launch(void* const* d_in, const int* in_sizes, int n_in,
                              void* d_out, int out_size, void* d_ws, size_t ws_size,
                              hipStream_t stream)
{
  const int* res_S = (const int*)d_in[29];
  const int* batch = (const int*)d_in[30];
  const int* row1  = (const int*)d_in[32];
  const int* col1  = (const int*)d_in[33];

  float* wsf = (float*)d_ws;
  size_t o = 0;
  int*   flag    = (int*)(wsf + o); o += 4;
  float* cvt     = wsf + o; o += CVT_RSV;
  float* wt      = wsf + o; o += 10*16384;
  int*   inv_row = (int*)(wsf + o); o += 256;
  int*   nbr     = (int*)(wsf + o); o += NRES*KNNK;
  float* resHn   = wsf + o; o += NROWS*HCH;
  bf16*  Qw16    = (bf16*)(wsf + o); o += NROWS*HCH/2;
  bf16*  Kw16    = (bf16*)(wsf + o); o += NROWS*HCH/2;
  bf16*  Vw16    = (bf16*)(wsf + o); o += NROWS*HCH/2;
  bf16*  TQw16   = (bf16*)(wsf + o); o += NROWS*HCH/2;
  bf16*  TKw16   = (bf16*)(wsf + o); o += NROWS*HCH/2;
  float* r_ws    = wsf + o; o += NEDGE*NH;
  bf16*  aVe16   = (bf16*)(wsf + o); o += (size_t)NEDGE*1792/2;
  float* dXe     = wsf + o; o += NEDGE*NCA*3;
  float* resH2   = wsf + o; o += NROWS*HCH;
  float* resX2   = wsf + o; o += NRES*NCA*3;
  float* lf      = wsf + o; o += 4*LC*HCH;
  bf16*  Klw16   = (bf16*)(wsf + o); o += 4*LC*HCH/2;
  bf16*  Vlw16   = (bf16*)(wsf + o); o += 4*LC*HCH/2;
  float* r1w     = wsf + o; o += NE1*NH;
  float* aVrw    = wsf + o; o += NE1*1792;
  float* aVlgw   = wsf + o; o += NE1*4096;
  unsigned* ctab = (unsigned*)(wsf + o); o += (size_t)NT*68;
  float* sig1T   = wsf + o; o += NT*4;
  float* Etab    = wsf + o; o += (size_t)NT*64;

  kcvt<<<CVB + NEB, 256, 0, stream>>>(
      d_in[0],d_in[1],d_in[2],d_in[3],d_in[4],d_in[5],d_in[6],d_in[7],d_in[8],
      d_in[9],d_in[10],d_in[11],d_in[12],d_in[13],d_in[14],d_in[15],d_in[16],
      d_in[17],d_in[18],d_in[19],d_in[20],d_in[21],d_in[22],d_in[23],d_in[24],
      d_in[25],d_in[26],d_in[27],d_in[28], cvt, flag, Etab);
  kprep<<<NGEMM + 640 + 1, 256, 0, stream>>>(cvt, Etab, row1, ctab, sig1T, wt, inv_row);
  kProjAll<<<800, 256, 0, stream>>>(cvt, wt, batch, resHn, Qw16, Kw16, Vw16, TQw16, TKw16,
                                    nbr, lf, Klw16, Vlw16);
  k3_edge<<<NEDGE, 256, 0, stream>>>(cvt, res_S, nbr, Qw16, Kw16, TQw16, TKw16, Vw16, ctab,
                                     r_ws, aVe16, dXe);
  k4_agg<<<NRES, 512, 0, stream>>>(cvt, res_S, inv_row, r_ws, aVe16, dXe, resHn, wt, flag,
                                   resH2, resX2, d_out);
  k6_lig<<<NE1*NH, 256, 0, stream>>>(cvt, res_S, row1, col1, resX2, Qw16, Klw16, Vw16, Vlw16, sig1T,
                                     r1w, aVrw, aVlgw);
  k78_final<<<384, 256, 0, stream>>>(inv_row, res_S, col1, resH2, aVrw, r1w, aVlgw, lf,
                                     wt, flag, d_out);
}

// Round 9
// 225.591 us; speedup vs baseline: 1.1828x; 1.1828x over previous
//
#include <hip/hip_runtime.h>
#include <hip/hip_bf16.h>
#include <math.h>

typedef __hip_bfloat16 bf16;

#define NRES 256
#define LC   32
#define HCH  128
#define ECH  64
#define NH   4
#define NCA  14
#define KNNK 8
#define DH   32
#define NKE  (NRES*KNNK)      // 2048
#define NEDGE (NKE+NRES)      // 2304
#define NE1  64
#define NROWS (NRES*NCA)      // 3584

// distance tables: nearest-neighbor, h=1/256, domain [0,12]
#define NT     3073
#define TSCALE 256.0f
#define DMAXT  12.0f

// ---- fp32 converted-input region offsets (floats) ----
#define O_RESH   0
#define O_RESX   458752
#define O_LPOS   469504
#define O_LFEAT  469888
#define O_LMASK  486272
#define O_LNG    486400
#define O_LNB    486528
#define O_LN1G   486656
#define O_LN1B   486784
#define O_WQ     486912
#define O_WK     503296
#define O_WV     519680
#define O_WKL    536064
#define O_WVL    552448
#define O_WO     568832
#define O_WOL    585216
#define O_WOL1   601600
#define O_TIW1   617984
#define O_TIB1   658944
#define O_TIW2   659072
#define O_TIB2   659200
#define O_SDW1   659204
#define O_SDB1   667396
#define O_SDW2   667524
#define O_SDB2   668036
#define O_SD1W1  668040
#define O_SD1B1  676232
#define O_SD1W2  676360
#define O_SD1B2  676872
#define TOTCVT   676876
#define CVT_RSV  676880

#define OUTX_OFF 458752
#define OUTL_OFF 469504

#define CVB  ((TOTCVT+255)/256)          // 2645 convert blocks
#define NEB  ((NT*64+255)/256)           // 769 E-table blocks
#define NGEMM 291                        // 97 row-tiles x 3 matrices

__constant__ int c_counts[21] = {14,5,11,8,8,6,9,9,4,10,8,8,9,8,11,7,6,7,14,12,7};

using bfrag = __attribute__((ext_vector_type(8))) short;   // 8 bf16 (4 VGPRs)
using f32x4 = __attribute__((ext_vector_type(4))) float;   // 4 fp32

__device__ __forceinline__ float b2f(bf16 x){ return __bfloat162float(x); }
__device__ __forceinline__ float sspf(float x){
  return fmaxf(x,0.f) + log1pf(expf(-fabsf(x))) - 0.6931471805599453f;
}
__device__ __forceinline__ float bflo(unsigned u){ return __uint_as_float(u<<16); }
__device__ __forceinline__ float bfhi(unsigned u){ return __uint_as_float(u & 0xffff0000u); }
__device__ __forceinline__ unsigned short f2bs(float v){ bf16 b=__float2bfloat16(v); return *(unsigned short*)&b; }
__device__ __forceinline__ unsigned pack2(float a, float b){
  return (unsigned)f2bs(a) | ((unsigned)f2bs(b)<<16);
}
__device__ __forceinline__ int ccount(int s){ return c_counts[s<0?0:(s>20?20:s)]; }
__device__ __forceinline__ void storeOut(void* out, int isbf, int idx, float v){
  if (isbf) ((bf16*)out)[idx] = __float2bfloat16(v);
  else      ((float*)out)[idx] = v;
}

// ---------------------------------------------------------------- kcvt: inputs -> fp32 + E-table blocks
__global__ __launch_bounds__(256) void kcvt(
    const void* s0,const void* s1,const void* s2,const void* s3,const void* s4,
    const void* s5,const void* s6,const void* s7,const void* s8,const void* s9,
    const void* s10,const void* s11,const void* s12,const void* s13,const void* s14,
    const void* s15,const void* s16,const void* s17,const void* s18,const void* s19,
    const void* s20,const void* s21,const void* s22,const void* s23,const void* s24,
    const void* s25,const void* s26,const void* s27,const void* s28,
    float* __restrict__ dst, int* __restrict__ flag, float* __restrict__ etab)
{
  int bb = blockIdx.x;
  int tid = threadIdx.x;
  if (bb >= CVB){
    int idx = (bb - CVB)*256 + tid;
    if (idx < NT*64){
      int bq = idx >> 6, k = idx & 63;
      const float step = 10.0f/63.0f;
      const float coef = -0.5f/(step*step);
      float t = (float)bq*(1.0f/256.0f) - step*(float)k;
      etab[idx] = expf(coef*t*t);
    }
    return;
  }
  __shared__ int sflag;
  if (tid < 64){
    unsigned w = ((const unsigned*)s0)[tid];
    unsigned lo = w & 0xFFFFu;
    int ee = (lo >> 7) & 0xFF;
    int good = (lo == 0u) || (ee >= 121 && ee <= 133);
    unsigned long long m = __ballot(good);
    if (tid == 0){
      sflag = (__popcll(m) >= 40) ? 1 : 0;
      if (blockIdx.x == 0) flag[0] = sflag;
    }
  }
  __syncthreads();
  int isbf = sflag;
  int g = bb*256 + tid;
  if (g >= TOTCVT) return;
  const void* src; int l;
  if      (g < O_RESX ) { src=s0;  l=g; }
  else if (g < O_LPOS ) { src=s1;  l=g-O_RESX; }
  else if (g < O_LFEAT) { src=s2;  l=g-O_LPOS; }
  else if (g < O_LMASK) { src=s3;  l=g-O_LFEAT; }
  else if (g < O_LNG  ) { src=s4;  l=g-O_LMASK; }
  else if (g < O_LNB  ) { src=s5;  l=g-O_LNG; }
  else if (g < O_LN1G ) { src=s6;  l=g-O_LNB; }
  else if (g < O_LN1B ) { src=s7;  l=g-O_LN1G; }
  else if (g < O_WQ   ) { src=s8;  l=g-O_LN1B; }
  else if (g < O_WK   ) { src=s9;  l=g-O_WQ; }
  else if (g < O_WV   ) { src=s10; l=g-O_WK; }
  else if (g < O_WKL  ) { src=s11; l=g-O_WV; }
  else if (g < O_WVL  ) { src=s12; l=g-O_WKL; }
  else if (g < O_WO   ) { src=s13; l=g-O_WVL; }
  else if (g < O_WOL  ) { src=s14; l=g-O_WO; }
  else if (g < O_WOL1 ) { src=s15; l=g-O_WOL; }
  else if (g < O_TIW1 ) { src=s16; l=g-O_WOL1; }
  else if (g < O_TIB1 ) { src=s17; l=g-O_TIW1; }
  else if (g < O_TIW2 ) { src=s18; l=g-O_TIB1; }
  else if (g < O_TIB2 ) { src=s19; l=g-O_TIW2; }
  else if (g < O_SDW1 ) { src=s20; l=0; }
  else if (g < O_SDB1 ) { src=s21; l=g-O_SDW1; }
  else if (g < O_SDW2 ) { src=s22; l=g-O_SDB1; }
  else if (g < O_SDB2 ) { src=s23; l=g-O_SDW2; }
  else if (g < O_SD1W1) { src=s24; l=g-O_SDB2; }
  else if (g < O_SD1B1) { src=s25; l=g-O_SD1W1; }
  else if (g < O_SD1W2) { src=s26; l=g-O_SD1B1; }
  else if (g < O_SD1B2) { src=s27; l=g-O_SD1W2; }
  else                  { src=s28; l=g-O_SD1B2; }
  float v = isbf ? b2f(((const bf16*)src)[l]) : ((const float*)src)[l];
  dst[g] = v;
}

// ---------------------------------------------------------------- kprep: table GEMM + transpose + inv_row
// ctab row (68 u32, 272B): [0]=sig01 [1]=sig23 [2+t]=c(2t,2t+1) t=0..63, [66..67]=0
__global__ __launch_bounds__(256) void kprep(const float* __restrict__ cvt, const float* __restrict__ Etab,
    const int* __restrict__ row1,
    unsigned* __restrict__ ctab, float* __restrict__ sig1T,
    float* __restrict__ wt, int* __restrict__ inv_row)
{
  int b = blockIdx.x, tid = threadIdx.x;
  if (b >= NGEMM){
    int cb = b - NGEMM;
    if (cb < 640){
      int gid = cb*256 + tid;
      int m = gid >> 14;
      int j = gid & 16383;
      int oo = j >> 7, c = j & 127;
      float v;
      switch(m){
        case 0: v = cvt[O_WQ  + j]; break;
        case 1: v = cvt[O_WK  + j]; break;
        case 2: v = cvt[O_WV  + j]; break;
        case 3: v = cvt[O_WO  + j]; break;
        case 4: v = cvt[O_WKL + j]; break;
        case 5: v = cvt[O_WVL + j]; break;
        case 6: v = cvt[O_WOL + j]; break;
        case 7: v = cvt[O_WOL1+ j]; break;
        case 8: v = cvt[O_TIW1 + oo*320 + c]; break;
        default:v = cvt[O_TIW1 + oo*320 + 128 + c]; break;
      }
      wt[m*16384 + c*128 + oo] = v;
    } else {
      inv_row[tid] = -1;
      __syncthreads();
      if (tid < NE1) inv_row[row1[tid] & 255] = tid;
    }
    return;
  }
  // GEMM tile: 32 table rows x 128 outputs for matrix m (0=Ti_c, 1=SDW1, 2=SD1W1)
  __shared__ float Wl[128*68];
  __shared__ float Et[32*68];
  __shared__ float H[32*132];
  __shared__ float W2[4*132];
  __shared__ float W2b[4];
  int mt = b % 97, m = b / 97;
  int r0 = mt*32;
  int nr = (NT - r0 < 32) ? (NT - r0) : 32;

  for (int idx=tid; idx<8192; idx+=256){
    int o=idx>>6, k=idx&63;
    float v = (m==0) ? cvt[O_TIW1 + o*320 + 256 + k]
            : (m==1) ? cvt[O_SDW1 + idx]
                     : cvt[O_SD1W1 + idx];
    Wl[o*68+k] = v;
  }
  for (int idx=tid; idx<nr*64; idx+=256){
    int r=idx>>6, k=idx&63;
    Et[r*68+k] = Etab[(size_t)(r0+r)*64 + k];
  }
  if (m >= 1){
    int wbase = (m==1)? O_SDW2 : O_SD1W2;
    int bbase = (m==1)? O_SDB2 : O_SD1B2;
    for (int idx=tid; idx<512; idx+=256)
      W2[(idx>>7)*132 + (idx&127)] = cvt[wbase + idx];
    if (tid < 4) W2b[tid] = cvt[bbase + tid];
  }
  __syncthreads();

  int o = tid & 127, g = tid >> 7;
  int boff = (m==0)? O_TIB1 : (m==1)? O_SDB1 : O_SD1B1;
  float bias = cvt[boff + o];
  float acc[16];
  #pragma unroll
  for (int i=0;i<16;i++) acc[i] = bias;
  const float* wrow = Wl + o*68;
  const float* ebase = Et + g*16*68;
  for (int kc=0; kc<16; kc++){
    float4 w4 = *(const float4*)(wrow + kc*4);
    #pragma unroll
    for (int i=0;i<16;i++){
      float4 e4 = *(const float4*)(ebase + i*68 + kc*4);
      acc[i] += e4.x*w4.x;
      acc[i] += e4.y*w4.y;
      acc[i] += e4.z*w4.z;
      acc[i] += e4.w*w4.w;
    }
  }

  if (m == 0){
    #pragma unroll
    for (int i=0;i<16;i++){
      int row = r0 + g*16 + i;
      float c = acc[i];
      float cn = __shfl_xor(c, 1);
      if (row < NT && !(o&1))
        ctab[(size_t)row*68 + 2 + (o>>1)] = pack2(c, cn);
    }
    if (o < 2 && g == 0){
      for (int i=0;i<32;i++){
        int row = r0 + i;
        if (row < NT) ctab[(size_t)row*68 + 66 + o] = 0u;
      }
    }
    return;
  }
  // m>=1: relu -> H, then 128->4 tail dots
  #pragma unroll
  for (int i=0;i<16;i++)
    H[(g*16+i)*132 + o] = fmaxf(acc[i], 0.f);
  __syncthreads();
  if (tid < 128){
    int r = tid >> 2, hh = tid & 3;
    int row = r0 + r;
    if (r < nr){
      float s = W2b[hh];
      const float* hr = H + r*132;
      const float* w2r = W2 + hh*132;
      for (int o2=0;o2<128;o2++) s += hr[o2]*w2r[o2];
      if (m == 1){
        float s1 = __shfl_down(s,1);
        float s2 = __shfl_down(s,2);
        float s3 = __shfl_down(s,3);
        if (hh == 0){
          ctab[(size_t)row*68 + 0] = pack2(s, s1);
          ctab[(size_t)row*68 + 1] = pack2(s2, s3);
        }
      } else {
        sig1T[row*4 + hh] = s;
      }
    }
  }
}

// ------------------------------------------------- kProjAll: b<672 LN+proj tiles; 672..735 KNN; 736..799 ligand
__global__ __launch_bounds__(256) void kProjAll(
    const float* __restrict__ cvt, const float* __restrict__ wt, const int* __restrict__ batch,
    float* __restrict__ resHn, bf16* __restrict__ Qw16, bf16* __restrict__ Kw16,
    bf16* __restrict__ Vw16, bf16* __restrict__ TQw16, bf16* __restrict__ TKw16,
    int* __restrict__ nbr, float* __restrict__ lf, bf16* __restrict__ Klw16, bf16* __restrict__ Vlw16)
{
  __shared__ float Xs[16*129];
  __shared__ float x2[2][HCH];
  __shared__ float sred2[2][2];
  int bb = blockIdx.x, tid = threadIdx.x;

  if (bb < 672){
    int m = bb / 224;
    int rt = (bb % 224) * 16;
    for (int i=tid; i<16*128; i+=256){
      int r=i>>7, c=i&127;
      Xs[r*129+c] = cvt[O_RESH + (rt+r)*HCH + c];
    }
    __syncthreads();
    {
      int wave = tid>>6, lane = tid&63;
      int r = wave*4 + (lane>>4);
      int cb = lane & 15;
      float s=0;
      #pragma unroll
      for (int j=0;j<8;j++) s += Xs[r*129 + cb + 16*j];
      #pragma unroll
      for (int off=1; off<16; off<<=1) s += __shfl_xor(s, off);
      float mu = s*(1.f/HCH);
      float q=0;
      #pragma unroll
      for (int j=0;j<8;j++){ float dv = Xs[r*129+cb+16*j]-mu; q += dv*dv; }
      #pragma unroll
      for (int off=1; off<16; off<<=1) q += __shfl_xor(q, off);
      float inv = rsqrtf(q*(1.f/HCH) + 1e-5f);
      #pragma unroll
      for (int j=0;j<8;j++){
        int c = cb + 16*j;
        float xh = (Xs[r*129+c]-mu)*inv*cvt[O_LNG+c] + cvt[O_LNB+c];
        Xs[r*129+c] = xh;
        if (m==0) resHn[(rt+r)*HCH+c] = xh;
      }
    }
    __syncthreads();
    int tc = (tid & 31) * 4;
    int tr = (tid >> 5) * 2;
    const float* W = wt + m*16384;
    float a00=0,a01=0,a02=0,a03=0, a10=0,a11=0,a12=0,a13=0;
    for (int c=0;c<HCH;c++){
      float4 w4 = *(const float4*)(W + c*128 + tc);
      float x0 = Xs[tr*129 + c];
      float x1 = Xs[(tr+1)*129 + c];
      a00 += x0*w4.x; a01 += x0*w4.y; a02 += x0*w4.z; a03 += x0*w4.w;
      a10 += x1*w4.x; a11 += x1*w4.y; a12 += x1*w4.z; a13 += x1*w4.w;
    }
    bf16* out = (m==0)? Qw16 : (m==1)? Kw16 : Vw16;
    {
      unsigned* o0 = (unsigned*)(out + (rt+tr  )*HCH + tc);
      unsigned* o1 = (unsigned*)(out + (rt+tr+1)*HCH + tc);
      o0[0]=pack2(a00,a01); o0[1]=pack2(a02,a03);
      o1[0]=pack2(a10,a11); o1[1]=pack2(a12,a13);
    }
    if (m == 2) return;
    __syncthreads();
    Xs[tr*129+tc]=a00; Xs[tr*129+tc+1]=a01; Xs[tr*129+tc+2]=a02; Xs[tr*129+tc+3]=a03;
    Xs[(tr+1)*129+tc]=a10; Xs[(tr+1)*129+tc+1]=a11; Xs[(tr+1)*129+tc+2]=a12; Xs[(tr+1)*129+tc+3]=a13;
    __syncthreads();
    const float* W2 = wt + (8+m)*16384;
    a00=0;a01=0;a02=0;a03=0; a10=0;a11=0;a12=0;a13=0;
    for (int c=0;c<HCH;c++){
      float4 w4 = *(const float4*)(W2 + c*128 + tc);
      float x0 = Xs[tr*129 + c];
      float x1 = Xs[(tr+1)*129 + c];
      a00 += x0*w4.x; a01 += x0*w4.y; a02 += x0*w4.z; a03 += x0*w4.w;
      a10 += x1*w4.x; a11 += x1*w4.y; a12 += x1*w4.z; a13 += x1*w4.w;
    }
    bf16* out2 = m ? TKw16 : TQw16;
    {
      unsigned* o0 = (unsigned*)(out2 + (rt+tr  )*HCH + tc);
      unsigned* o1 = (unsigned*)(out2 + (rt+tr+1)*HCH + tc);
      o0[0]=pack2(a00,a01); o0[1]=pack2(a02,a03);
      o1[0]=pack2(a10,a11); o1[1]=pack2(a12,a13);
    }
    return;
  }

  if (bb < 736){
    // KNN: one wave per residue
    int wave = tid>>6, lane = tid&63;
    int n = (bb-672)*4 + wave;
    float cx = cvt[O_RESX+(n*NCA+1)*3+0];
    float cy = cvt[O_RESX+(n*NCA+1)*3+1];
    float cz = cvt[O_RESX+(n*NCA+1)*3+2];
    int bn = batch[n];
    float d2v[4]; int idv[4];
    #pragma unroll
    for (int t=0;t<4;t++){
      int j = lane + 64*t;
      float jx = cvt[O_RESX+(j*NCA+1)*3+0];
      float jy = cvt[O_RESX+(j*NCA+1)*3+1];
      float jz = cvt[O_RESX+(j*NCA+1)*3+2];
      float dx=cx-jx, dy=cy-jy, dz=cz-jz;
      float d2 = dx*dx+dy*dy+dz*dz;
      bool bad = (batch[j]!=bn) || (j==n);
      d2v[t] = bad ? INFINITY : d2;
      idv[t] = j;
    }
    for (int k=0;k<KNNK;k++){
      float dm = d2v[0]; int im = idv[0];
      #pragma unroll
      for (int t=1;t<4;t++)
        if (d2v[t]<dm || (d2v[t]==dm && idv[t]<im)){ dm=d2v[t]; im=idv[t]; }
      #pragma unroll
      for (int off=1; off<64; off<<=1){
        float dn = __shfl_xor(dm, off);
        int   in = __shfl_xor(im, off);
        if (dn<dm || (dn==dm && in<im)){ dm=dn; im=in; }
      }
      if (lane==0) nbr[n*KNNK+k] = im;
      #pragma unroll
      for (int t=0;t<4;t++) if (idv[t]==im) d2v[t] = INFINITY;
    }
    return;
  }

  // ligand LN + Kl/Vl: 2 rows per block
  int row = tid>>7, t = tid&127;
  int rb = (bb-736)*2 + row;
  float v = cvt[O_LFEAT + rb*HCH + t];
  float s=v;
  for (int off=1; off<64; off<<=1) s += __shfl_xor(s, off);
  if ((t&63)==0) sred2[row][t>>6]=s;
  __syncthreads();
  float mu=(sred2[row][0]+sred2[row][1])*(1.f/HCH);
  __syncthreads();
  float d=v-mu; s=d*d;
  for (int off=1; off<64; off<<=1) s += __shfl_xor(s, off);
  if ((t&63)==0) sred2[row][t>>6]=s;
  __syncthreads();
  float var=(sred2[row][0]+sred2[row][1])*(1.f/HCH);
  float xh = d*rsqrtf(var+1e-5f)*cvt[O_LN1G+t] + cvt[O_LN1B+t];
  x2[row][t]=xh; lf[rb*HCH+t]=xh;
  __syncthreads();
  const float* WKlt = wt + 4*16384;
  const float* WVlt = wt + 5*16384;
  float aK=0.f, aV=0.f;
  for (int c=0;c<HCH;c++){
    float xc=x2[row][c];
    aK += xc*WKlt[c*128+t];
    aV += xc*WVlt[c*128+t];
  }
  Klw16[rb*HCH+t]=__float2bfloat16(aK);
  Vlw16[rb*HCH+t]=__float2bfloat16(aV);
}

// ------------------------------------------------- k3: fused residue-edge; MFMA qk/aV, bf16 ctab, LDS overlay
#define PR1(cbu, tau, kau, wl, wh) \
  fa += fmaxf(bflo(tau)+bflo(kau)+bflo(cbu),0.f)*(wl) + fmaxf(bfhi(tau)+bfhi(kau)+bfhi(cbu),0.f)*(wh);

__global__ __launch_bounds__(256) void k3_edge(
    const float* __restrict__ cvt, const int* __restrict__ res_S, const int* __restrict__ nbr,
    const bf16* __restrict__ Qw16, const bf16* __restrict__ Kw16,
    const bf16* __restrict__ TQw16, const bf16* __restrict__ TKw16,
    const bf16* __restrict__ Vw16, const unsigned* __restrict__ ctab,
    float* __restrict__ r_ws, bf16* __restrict__ aVe16, float* __restrict__ dXe)
{
  __shared__ __align__(16) unsigned char UB[8192];
  __shared__ unsigned Tqp[14*66], Tkp[14*66];
  __shared__ float LG[4*16*17];
  __shared__ float FR[196];
  __shared__ __align__(16) float tw2s[132];
  __shared__ float tb2s[1], Xr[42], Xc[42], amr[14], amc[14], rpart[56], cnts[2];
  unsigned char* QbB = UB;
  unsigned char* KbB = UB + 4096;
  unsigned char* VtB = UB;

  int b = blockIdx.x, tid = threadIdx.x;
  int rr = b & 255, slot = b >> 8;
  int e  = (slot < 8) ? (rr*8 + slot) : (2048 + rr);
  int cc = (slot < 8) ? (nbr[rr*8 + slot] & 255) : rr;

  const unsigned* TQ32 = (const unsigned*)TQw16;
  const unsigned* TK32 = (const unsigned*)TKw16;

  {
    int row = tid >> 4, s16 = tid & 15;
    uint4 qv = {0u,0u,0u,0u}, kv = {0u,0u,0u,0u};
    if (row < 14){
      qv = ((const uint4*)(Qw16 + (size_t)rr*1792))[tid];
      kv = ((const uint4*)(Kw16 + (size_t)cc*1792))[tid];
    }
    int off = row*256 + ((s16 ^ (row & 7)) << 4);
    *(uint4*)(QbB + off) = qv;
    *(uint4*)(KbB + off) = kv;
  }
  for (int i = tid; i < 14*66; i += 256){
    int p = i/66, t = i - p*66;
    Tqp[i] = (t<64) ? TQ32[rr*896 + p*64 + t] : 0u;
    Tkp[i] = (t<64) ? TK32[cc*896 + p*64 + t] : 0u;
  }
  if (tid < 132) tw2s[tid] = (tid<128) ? cvt[O_TIW2+tid] : 0.f;
  if (tid == 132) tb2s[0] = cvt[O_TIB2];
  if (tid >= 136 && tid < 178){
    int i=tid-136; int p=i/3, jx=i%3;
    Xr[i] = cvt[O_RESX+(rr*NCA+p)*3+jx];
    Xc[i] = cvt[O_RESX+(cc*NCA+p)*3+jx];
  }
  if (tid >= 242 && tid < 242+NCA){
    int p=tid-242;
    amr[p] = (p < ccount(res_S[rr])) ? 1.f : 0.f;
    amc[p] = (p < ccount(res_S[cc])) ? 1.f : 0.f;
  }
  __syncthreads();

  {
    int w = tid >> 6, l = tid & 63;
    int mrow = l & 15, s = l >> 4;
    int aoff = mrow*256 + (((w*4 + s) ^ (mrow & 7)) << 4);
    bfrag a = *(const bfrag*)(QbB + aoff);
    bfrag bkf = *(const bfrag*)(KbB + aoff);
    f32x4 dacc = {0.f,0.f,0.f,0.f};
    dacc = __builtin_amdgcn_mfma_f32_16x16x32_bf16(a, bkf, dacc, 0, 0, 0);
    const float isq = 0.17677669529663687f;
    #pragma unroll
    for (int r=0;r<4;r++){
      int p = s*4 + r;
      LG[w*272 + p*17 + mrow] = dacc[r]*isq;
    }
  }

  float sgx=0.f, sgy=0.f, sgz=0.f, sgw=0.f, invd_r=0.f;
  int havePair = (tid < 196);
  if (havePair){
    int p = tid/14, q = tid%14;
    float dx=Xr[p*3]-Xc[q*3], dy=Xr[p*3+1]-Xc[q*3+1], dz=Xr[p*3+2]-Xc[q*3+2];
    float d = sqrtf(fmaxf(dx*dx+dy*dy+dz*dz, 1e-12f));
    invd_r = 1.f/(d + 1e-5f);
    int i0 = (int)(fminf(d, DMAXT)*TSCALE + 0.5f);
    const uint4* crow = (const uint4*)ctab + (size_t)i0*17;
    const unsigned* TqpRow = Tqp + p*66;
    const unsigned* TkpRow = Tkp + q*66;
    uint4 h0 = crow[0];
    sgx = bflo(h0.x); sgy = bfhi(h0.x); sgz = bflo(h0.y); sgw = bfhi(h0.y);
    float fa = tb2s[0];
    {
      uint2 ta = *(const uint2*)(TqpRow);
      uint2 ka = *(const uint2*)(TkpRow);
      float4 w0 = *(const float4*)(tw2s);
      PR1(h0.z, ta.x, ka.x, w0.x, w0.y);
      PR1(h0.w, ta.y, ka.y, w0.z, w0.w);
    }
    #pragma unroll 4
    for (int j=1;j<17;j++){
      uint4 ch = crow[j];
      int t = 4*j - 2;
      uint2 ta0 = *(const uint2*)(TqpRow + t);
      uint2 ta1 = *(const uint2*)(TqpRow + t + 2);
      uint2 ka0 = *(const uint2*)(TkpRow + t);
      uint2 ka1 = *(const uint2*)(TkpRow + t + 2);
      float4 w0 = *(const float4*)(tw2s + 2*t);
      float4 w1 = *(const float4*)(tw2s + 2*t + 4);
      PR1(ch.x, ta0.x, ka0.x, w0.x, w0.y);
      PR1(ch.y, ta0.y, ka0.y, w0.z, w0.w);
      PR1(ch.z, ta1.x, ka1.x, w1.x, w1.y);
      PR1(ch.w, ta1.y, ka1.y, w1.z, w1.w);
    }
    FR[tid] = fa;
  }
  __syncthreads();

  if (havePair){
    int p = tid/14, q = tid%14;
    LG[      p*17+q] += sgx;
    LG[272 + p*17+q] += sgy;
    LG[544 + p*17+q] += sgz;
    LG[816 + p*17+q] += sgw;
  }
  for (int i = tid; i < 128*16; i += 256){
    int qp = i >> 7, d = i & 127;
    int qq = qp*2;
    unsigned pv = 0u;
    if (qq < 14){
      const unsigned short* vs = (const unsigned short*)(Vw16 + (size_t)cc*1792);
      unsigned short v0 = vs[qq*128 + d];
      unsigned short v1 = vs[(qq+1)*128 + d];
      pv = (unsigned)v0 | ((unsigned)v1 << 16);
    }
    int slotq = qq >> 3;
    int off = d*64 + ((slotq ^ (d & 3)) << 4) + (qq & 7)*2;
    *(unsigned*)(VtB + off) = pv;
  }
  __syncthreads();

  if (tid < 56){
    int h=tid/14, pp=tid%14;
    float ap = amr[pp];
    float* rowp = LG + h*272 + pp*17;
    float row[NCA];
    float s=0;
    #pragma unroll
    for (int qq=0;qq<NCA;qq++){ row[qq]=rowp[qq]; s += row[qq]*amc[qq]; }
    rpart[h*14+pp] = s*ap;
    float m=-INFINITY;
    #pragma unroll
    for (int qq=0;qq<NCA;qq++) m=fmaxf(m,row[qq]);
    float sum=0;
    #pragma unroll
    for (int qq=0;qq<NCA;qq++){ row[qq]=expf(row[qq]-m); sum+=row[qq]; }
    float inv=1.f/sum, s2=0;
    #pragma unroll
    for (int qq=0;qq<NCA;qq++){ row[qq]=row[qq]*inv*ap*amc[qq]; s2+=row[qq]; }
    float inv2=1.f/(s2+1e-7f);
    #pragma unroll
    for (int qq=0;qq<NCA;qq++) rowp[qq]=row[qq]*inv2;
  }
  if (tid == 56){
    float sr=0, sc=0;
    for (int i=0;i<NCA;i++){ sr+=amr[i]; sc+=amc[i]; }
    cnts[0]=sr; cnts[1]=sc;
  }
  __syncthreads();
  if (tid < NH){
    float s=0;
    for (int pp=0;pp<NCA;pp++) s += rpart[tid*14+pp];
    r_ws[e*NH+tid] = s/(cnts[0]*cnts[1]);
  }
  if (tid < 196){
    int p=tid/14, q=tid%14;
    float ma = 0.25f*(LG[p*17+q] + LG[272+p*17+q] + LG[544+p*17+q] + LG[816+p*17+q]);
    FR[tid] *= ma * invd_r;
  }

  {
    int w = tid >> 6, l = tid & 63;
    int mrow = l & 15, s = l >> 4;
    bfrag pa;
    if (s < 2){
      const float* ar = LG + w*272 + mrow*17 + s*8;
      #pragma unroll
      for (int j=0;j<8;j++) pa[j] = (short)f2bs(ar[j]);
    } else {
      #pragma unroll
      for (int j=0;j<8;j++) pa[j] = (short)0;
    }
    #pragma unroll
    for (int half=0; half<2; half++){
      int dg = w*32 + half*16 + mrow;
      int boff = dg*64 + ((s ^ (dg & 3)) << 4);
      bfrag pb = *(const bfrag*)(VtB + boff);
      f32x4 dd = {0.f,0.f,0.f,0.f};
      dd = __builtin_amdgcn_mfma_f32_16x16x32_bf16(pa, pb, dd, 0, 0, 0);
      #pragma unroll
      for (int r=0;r<4;r++){
        int p = s*4 + r;
        if (p < NCA)
          aVe16[(size_t)e*1792 + w*448 + p*32 + half*16 + mrow] = __float2bfloat16(dd[r]);
      }
    }
  }
  __syncthreads();

  if (tid < NCA*3){
    int pp = tid/3, jx = tid%3;
    float a=0;
    #pragma unroll
    for (int qq=0;qq<NCA;qq++){
      float diff = Xr[pp*3+jx]-Xc[qq*3+jx];
      a += FR[pp*14+qq]*diff;
    }
    dXe[(e*NCA+pp)*3+jx] = a;
  }
}

// ------------------------------------------------- k4: per-residue beta + updH + WO + dX (256 threads, R3 form)
__global__ __launch_bounds__(256) void k4_agg(
    const float* __restrict__ cvt, const int* __restrict__ res_S, const int* __restrict__ inv_row,
    const float* __restrict__ r_ws, const bf16* __restrict__ aVe16, const float* __restrict__ dXe,
    const float* __restrict__ resHn, const float* __restrict__ wt, const int* __restrict__ flag,
    float* __restrict__ resH2, float* __restrict__ resX2, void* __restrict__ d_out)
{
  int n = blockIdx.x, tid = threadIdx.x;
  __shared__ float beta[9][NH];
  __shared__ float betam[9];
  __shared__ float Xs[NCA][HCH];
  if (tid < NH){
    int h = tid;
    float rv[9], m=-INFINITY;
    #pragma unroll
    for (int k=0;k<9;k++){
      int ek = (k<KNNK)? n*KNNK+k : NKE+n;
      rv[k] = r_ws[ek*NH+h];
      m = fmaxf(m, rv[k]);
    }
    float s=0;
    #pragma unroll
    for (int k=0;k<9;k++){ rv[k]=expf(rv[k]-m); s+=rv[k]; }
    #pragma unroll
    for (int k=0;k<9;k++) beta[k][h]=rv[k]/s;
  }
  __syncthreads();
  if (tid < 9) betam[tid] = 0.25f*(beta[tid][0]+beta[tid][1]+beta[tid][2]+beta[tid][3]);
  int col = tid & 127, ph = tid >> 7;
  int h = col>>5, dd = col&31;
  float bh[9];
  #pragma unroll
  for (int k=0;k<9;k++) bh[k]=beta[k][h];
  #pragma unroll
  for (int i=0;i<7;i++){
    int p = ph + 2*i;
    float u=0;
    #pragma unroll
    for (int k=0;k<9;k++){
      int ek = (k<KNNK)? n*KNNK+k : NKE+n;
      u += bh[k]*b2f(aVe16[ek*1792 + h*448 + p*32 + dd]);
    }
    Xs[p][col] = sspf(u);
  }
  __syncthreads();
  const float* WOt = wt + 3*16384;
  float acc[7];
  #pragma unroll
  for (int i=0;i<7;i++) acc[i]=0.f;
  for (int c=0;c<HCH;c++){
    float w = WOt[c*128+col];
    #pragma unroll
    for (int i=0;i<7;i++) acc[i] += Xs[ph+2*i][c]*w;
  }
  int cnt = ccount(res_S[n]);
  #pragma unroll
  for (int i=0;i<7;i++){
    int p = ph + 2*i;
    float am = (p<cnt)?1.f:0.f;
    float outv = (resHn[(n*NCA+p)*HCH+col] + acc[i])*am;
    resH2[(n*NCA+p)*HCH+col] = outv;
  }
  if (tid < NCA*3){
    int isbf = *flag;
    int p=tid/3, jx=tid%3;
    float s=0;
    #pragma unroll
    for (int k=0;k<9;k++){
      int ek=(k<KNNK)? n*KNNK+k : NKE+n;
      s += betam[k]*dXe[(ek*NCA+p)*3+jx];
    }
    float base = cvt[O_RESX+(n*NCA+p)*3+jx];
    float v = (inv_row[n]>=0) ? base + fminf(fmaxf(s,-3.f),3.f) : base;
    resX2[(n*NCA+p)*3+jx] = v;
    storeOut(d_out, isbf, OUTX_OFF + (n*NCA+p)*3+jx, v);
  }
}

// ------------------------------------------------- k6: ligand-edge per (edge,head); parallel softmax (R7 form)
__global__ __launch_bounds__(256) void k6_lig(
    const float* __restrict__ cvt, const int* __restrict__ res_S,
    const int* __restrict__ row1, const int* __restrict__ col1,
    const float* __restrict__ resX2, const bf16* __restrict__ Qw16, const bf16* __restrict__ Klw16,
    const bf16* __restrict__ Vw16, const bf16* __restrict__ Vlw16, const float* __restrict__ sig1T,
    float* __restrict__ r1_ws, float* __restrict__ aVr, float* __restrict__ aVlg)
{
  __shared__ float Bq[14*33], Vrs[14*33], Bk[32*33], Vls[32*33];
  __shared__ float LG[14*33], ALs[14*33];
  __shared__ float Xr[42], Lp[96], amr[14], lm[32], s2r[14], rpart[14], cnts[2];
  int bb = blockIdx.x, tid = threadIdx.x;
  int e = bb >> 2, h = bb & 3;
  int rr = row1[e] & 255, cb = col1[e] & 3;
  const unsigned* Q32  = (const unsigned*)Qw16;
  const unsigned* V32  = (const unsigned*)Vw16;
  const unsigned* Kl32 = (const unsigned*)Klw16;
  const unsigned* Vl32 = (const unsigned*)Vlw16;

  for (int i=tid; i<224; i+=256){
    int p=i>>4, dp=i&15;
    unsigned q2 = Q32[rr*896 + p*64 + h*16 + dp];
    unsigned v2 = V32[rr*896 + p*64 + h*16 + dp];
    Bq[p*33+2*dp]  = bflo(q2); Bq[p*33+2*dp+1]  = bfhi(q2);
    Vrs[p*33+2*dp] = bflo(v2); Vrs[p*33+2*dp+1] = bfhi(v2);
  }
  for (int i=tid; i<512; i+=256){
    int q=i>>4, dp=i&15;
    unsigned k2 = Kl32[cb*2048 + q*64 + h*16 + dp];
    unsigned w2 = Vl32[cb*2048 + q*64 + h*16 + dp];
    Bk[q*33+2*dp]  = bflo(k2); Bk[q*33+2*dp+1]  = bfhi(k2);
    Vls[q*33+2*dp] = bflo(w2); Vls[q*33+2*dp+1] = bfhi(w2);
  }
  if (tid >= 8 && tid < 50){ int i=tid-8; int p=i/3,jx=i%3; Xr[i]=resX2[(rr*NCA+p)*3+jx]; }
  if (tid >= 64 && tid < 160){ int i=tid-64; Lp[i]=cvt[O_LPOS + cb*96 + i]; }
  if (tid >= 160 && tid < 174) amr[tid-160]=((tid-160) < ccount(res_S[rr]))?1.f:0.f;
  if (tid >= 192 && tid < 224) lm[tid-192]=cvt[O_LMASK + cb*LC + tid-192];
  __syncthreads();

  const float isq=0.17677669529663687f;
  for (int pair=tid; pair<448; pair+=256){
    int p=pair>>5, q=pair&31;
    float dx=Xr[p*3]-Lp[q*3], dy=Xr[p*3+1]-Lp[q*3+1], dz=Xr[p*3+2]-Lp[q*3+2];
    float d=sqrtf(fmaxf(dx*dx+dy*dy+dz*dz,1e-12f));
    int i0=(int)(fminf(d,DMAXT)*TSCALE+0.5f);
    float sg = sig1T[i0*4+h];
    float qk=0;
    #pragma unroll
    for (int dd=0;dd<DH;dd++) qk += Bq[p*33+dd]*Bk[q*33+dd];
    LG[p*33+q] = qk*isq + sg;
  }
  __syncthreads();                          // LG ready

  // P1: row stats + held normalized row (224 threads: pp x 16 lanes x 2 q's)
  float a0=0.f, a1=0.f;
  if (tid < 224){
    int pp = tid>>4, qh = tid&15;
    float v0 = LG[pp*33+qh], v1 = LG[pp*33+qh+16];
    float l0 = lm[qh], l1 = lm[qh+16];
    float sl = v0*l0 + v1*l1;
    float mx = fmaxf(v0,v1);
    #pragma unroll
    for (int off=1; off<16; off<<=1){
      sl += __shfl_xor(sl,off);
      mx = fmaxf(mx, __shfl_xor(mx,off));
    }
    float e0=expf(v0-mx), e1=expf(v1-mx);
    float se=e0+e1;
    #pragma unroll
    for (int off=1; off<16; off<<=1) se += __shfl_xor(se,off);
    float inv=1.f/se, ap=amr[pp];
    float t0=e0*inv*ap*l0, t1=e1*inv*ap*l1;
    float s2=t0+t1;
    #pragma unroll
    for (int off=1; off<16; off<<=1) s2 += __shfl_xor(s2,off);
    float inv2=1.f/(s2+1e-7f);
    a0=t0*inv2; a1=t1*inv2;
    if (qh==0){ rpart[pp]=sl*ap; s2r[pp]=s2*inv2; }
  } else if (tid == 224){
    float sr=0; for (int i=0;i<NCA;i++) sr+=amr[i]; cnts[0]=sr;
  } else if (tid == 225){
    float sl=0; for (int i=0;i<LC;i++) sl+=lm[i]; cnts[1]=sl;
  }
  __syncthreads();

  if (tid==0){ float s=0; for (int pp=0;pp<NCA;pp++) s+=rpart[pp]; r1_ws[e*NH+h]=s/(cnts[0]*cnts[1]); }
  if (tid < 32){
    int qq=tid;
    float m=-INFINITY;
    for (int pp=0;pp<NCA;pp++) m=fmaxf(m,LG[pp*33+qq]);
    float sum=0;
    for (int pp=0;pp<NCA;pp++) sum+=expf(LG[pp*33+qq]-m);
    float inv=1.f/sum, lq=lm[qq];
    for (int pp=0;pp<NCA;pp++){
      float a=expf(LG[pp*33+qq]-m)*inv*amr[pp]*lq;
      ALs[pp*33+qq]=a/(s2r[pp]+1e-7f);
    }
  }
  __syncthreads();

  if (tid < 224){
    int pp = tid>>4, qh = tid&15;
    LG[pp*33+qh]    = a0;
    LG[pp*33+qh+16] = a1;
  }
  __syncthreads();

  for (int j=tid;j<448;j+=256){
    int pp=j>>5, dd=j&31;
    float acc=0;
    #pragma unroll
    for (int qq=0;qq<LC;qq++) acc += LG[pp*33+qq]*Vls[qq*33+dd];
    aVr[e*1792 + h*448 + j]=acc;
  }
  for (int j=tid;j<1024;j+=256){
    int qq=j>>5, dd=j&31;
    float acc=0;
    #pragma unroll
    for (int pp=0;pp<NCA;pp++) acc += ALs[pp*33+qq]*Vrs[pp*33+dd];
    aVlg[e*4096 + h*1024 + j]=acc;
  }
}

// ------------------------------------------------- k78: finalize res_H3 (0..255) + lf2 (256..383) (R7 form)
__global__ __launch_bounds__(256) void k78_final(
    const int* __restrict__ inv_row, const int* __restrict__ res_S, const int* __restrict__ col1,
    const float* __restrict__ resH2, const float* __restrict__ aVr,
    const float* __restrict__ r1_ws, const float* __restrict__ aVlg, const float* __restrict__ lf,
    const float* __restrict__ wt, const int* __restrict__ flag, void* __restrict__ d_out)
{
  int bb = blockIdx.x, tid = threadIdx.x;
  if (bb < 256){
    int n = bb;
    int e = inv_row[n];
    __shared__ float G[NCA][HCH];
    if (e>=0){
      for (int j=tid;j<NCA*HCH;j+=256){
        int h=j/448, rem=j%448, pp=rem>>5, dd=rem&31;
        G[pp][h*DH+dd] = sspf(aVr[e*1792+j]);
      }
    }
    __syncthreads();
    int col = tid & 127, ph = tid >> 7;
    float acc[7];
    #pragma unroll
    for (int i=0;i<7;i++) acc[i]=0.f;
    if (e>=0){
      const float* WOlt = wt + 6*16384;
      for (int c=0;c<HCH;c++){
        float w=WOlt[c*128+col];
        #pragma unroll
        for (int i=0;i<7;i++) acc[i]+=G[ph+2*i][c]*w;
      }
    }
    int cnt=ccount(res_S[n]);
    int isbf = *flag;
    #pragma unroll
    for (int i=0;i<7;i++){
      int p = ph + 2*i;
      float am=(p<cnt)?1.f:0.f;
      float v=(resH2[(n*NCA+p)*HCH+col]+acc[i])*am;
      storeOut(d_out, isbf, (n*NCA+p)*HCH+col, v);
    }
    return;
  }
  // lf2 path
  int rb = bb - 256;
  int bsel = rb>>5, q = rb&31;
  __shared__ float bw[NE1][NH];
  __shared__ float xs[HCH];
  __shared__ float r1s[256];
  __shared__ int cls[64];
  r1s[tid] = r1_ws[tid];
  if (tid < 64) cls[tid] = col1[tid] & 3;
  __syncthreads();
  {
    int e = tid>>2, h = tid&3;
    float v = 0.f;
    if (cls[e] == bsel){
      float m = -INFINITY;
      for (int ee=0; ee<NE1; ee++) if (cls[ee]==bsel) m = fmaxf(m, r1s[ee*4+h]);
      float s = 0;
      for (int ee=0; ee<NE1; ee++) if (cls[ee]==bsel) s += expf(r1s[ee*4+h]-m);
      v = expf(r1s[tid]-m)/s;
    }
    bw[e][h] = v;
  }
  __syncthreads();
  if (tid < 128){
    int h=tid>>5, dd=tid&31;
    float u=0;
    for (int e=0;e<NE1;e++) u += bw[e][h]*aVlg[e*4096 + h*1024 + q*32 + dd];
    xs[tid]=sspf(u);
  }
  __syncthreads();
  if (tid < 128){
    const float* WOl1t = wt + 7*16384;
    float acc=0;
    for (int c=0;c<HCH;c++) acc += xs[c]*WOl1t[c*128+tid];
    float v = lf[rb*HCH+tid] + acc;
    storeOut(d_out, *flag, OUTL_OFF + rb*HCH+tid, v);
  }
}

// ================================================================ launch
extern "C" void kernel_launch(void* const* d_in, const int* in_sizes, int n_in,
                              void* d_out, int out_size, void* d_ws, size_t ws_size,
                              hipStream_t stream)
{
  const int* res_S = (const int*)d_in[29];
  const int* batch = (const int*)d_in[30];
  const int* row1  = (const int*)d_in[32];
  const int* col1  = (const int*)d_in[33];

  float* wsf = (float*)d_ws;
  size_t o = 0;
  int*   flag    = (int*)(wsf + o); o += 4;
  float* cvt     = wsf + o; o += CVT_RSV;
  float* wt      = wsf + o; o += 10*16384;
  int*   inv_row = (int*)(wsf + o); o += 256;
  int*   nbr     = (int*)(wsf + o); o += NRES*KNNK;
  float* resHn   = wsf + o; o += NROWS*HCH;
  bf16*  Qw16    = (bf16*)(wsf + o); o += NROWS*HCH/2;
  bf16*  Kw16    = (bf16*)(wsf + o); o += NROWS*HCH/2;
  bf16*  Vw16    = (bf16*)(wsf + o); o += NROWS*HCH/2;
  bf16*  TQw16   = (bf16*)(wsf + o); o += NROWS*HCH/2;
  bf16*  TKw16   = (bf16*)(wsf + o); o += NROWS*HCH/2;
  float* r_ws    = wsf + o; o += NEDGE*NH;
  bf16*  aVe16   = (bf16*)(wsf + o); o += (size_t)NEDGE*1792/2;
  float* dXe     = wsf + o; o += NEDGE*NCA*3;
  float* resH2   = wsf + o; o += NROWS*HCH;
  float* resX2   = wsf + o; o += NRES*NCA*3;
  float* lf      = wsf + o; o += 4*LC*HCH;
  bf16*  Klw16   = (bf16*)(wsf + o); o += 4*LC*HCH/2;
  bf16*  Vlw16   = (bf16*)(wsf + o); o += 4*LC*HCH/2;
  float* r1w     = wsf + o; o += NE1*NH;
  float* aVrw    = wsf + o; o += NE1*1792;
  float* aVlgw   = wsf + o; o += NE1*4096;
  unsigned* ctab = (unsigned*)(wsf + o); o += (size_t)NT*68;
  float* sig1T   = wsf + o; o += NT*4;
  float* Etab    = wsf + o; o += (size_t)NT*64;

  kcvt<<<CVB + NEB, 256, 0, stream>>>(
      d_in[0],d_in[1],d_in[2],d_in[3],d_in[4],d_in[5],d_in[6],d_in[7],d_in[8],
      d_in[9],d_in[10],d_in[11],d_in[12],d_in[13],d_in[14],d_in[15],d_in[16],
      d_in[17],d_in[18],d_in[19],d_in[20],d_in[21],d_in[22],d_in[23],d_in[24],
      d_in[25],d_in[26],d_in[27],d_in[28], cvt, flag, Etab);
  kprep<<<NGEMM + 640 + 1, 256, 0, stream>>>(cvt, Etab, row1, ctab, sig1T, wt, inv_row);
  kProjAll<<<800, 256, 0, stream>>>(cvt, wt, batch, resHn, Qw16, Kw16, Vw16, TQw16, TKw16,
                                    nbr, lf, Klw16, Vlw16);
  k3_edge<<<NEDGE, 256, 0, stream>>>(cvt, res_S, nbr, Qw16, Kw16, TQw16, TKw16, Vw16, ctab,
                                     r_ws, aVe16, dXe);
  k4_agg<<<NRES, 256, 0, stream>>>(cvt, res_S, inv_row, r_ws, aVe16, dXe, resHn, wt, flag,
                                   resH2, resX2, d_out);
  k6_lig<<<NE1*NH, 256, 0, stream>>>(cvt, res_S, row1, col1, resX2, Qw16, Klw16, Vw16, Vlw16, sig1T,
                                     r1w, aVrw, aVlgw);
  k78_final<<<384, 256, 0, stream>>>(inv_row, res_S, col1, resH2, aVrw, r1w, aVlgw, lf,
                                     wt, flag, d_out);
}